// Round 8
// baseline (220.563 us; speedup 1.0000x reference)
//
#include <hip/hip_runtime.h>

#define SEQ 2048
#define DMODEL 1024
#define HEADS 16
#define DH 64
// fold (1/sqrt(64)) * log2(e) into Wq so scores arrive in exp2 domain
#define QSCALE 0.180336880f

typedef __attribute__((ext_vector_type(8))) short short8;
typedef __attribute__((ext_vector_type(4))) float f32x4;
typedef __attribute__((ext_vector_type(16))) float f32x16;
typedef __attribute__((ext_vector_type(2))) unsigned int uint2v;
typedef __attribute__((ext_vector_type(4))) unsigned int uint4v;

__device__ __forceinline__ ushort f2bf(float x) {
  union { float f; unsigned u; } v; v.f = x;
  return (ushort)((v.u + 0x7fffu + ((v.u >> 16) & 1u)) >> 16);
}

// async global->LDS, 16B per lane. LDS dest = wave-uniform base + lane*16.
__device__ __forceinline__ void gld16(const ushort* g, ushort* l) {
  __builtin_amdgcn_global_load_lds(
      (const __attribute__((address_space(1))) unsigned int*)g,
      (__attribute__((address_space(3))) unsigned int*)l, 16, 0, 0);
}

// ---------------------------------------------------------------------------
// Fused prologue. z=0/1: fp32->bf16 cast of patch/pixel (4x float4/thread).
// z=2..5: transpose-cast Wq*QSCALE / Wk / Wv / Wo to [N][K] bf16.
// ---------------------------------------------------------------------------
__global__ __launch_bounds__(256) void prologue(
    const float* __restrict__ patch, const float* __restrict__ pixel,
    const float* __restrict__ W0, const float* __restrict__ W1,
    const float* __restrict__ W2, const float* __restrict__ W3,
    ushort* __restrict__ pb, ushort* __restrict__ xb,
    ushort* __restrict__ O0, ushort* __restrict__ O1,
    ushort* __restrict__ O2, ushort* __restrict__ O3) {
  const int z = blockIdx.z;
  const int tx = threadIdx.x, ty = threadIdx.y;
  if (z < 2) {
    const float4* in = (const float4*)(z ? pixel : patch);
    ushort4* out = (ushort4*)(z ? xb : pb);
    const int base = (blockIdx.y * 32 + blockIdx.x) * 256 + ty * 32 + tx;
#pragma unroll
    for (int rep = 0; rep < 4; ++rep) {
      const int i = base + rep * 262144;
      float4 f = in[i];
      out[i] = make_ushort4(f2bf(f.x), f2bf(f.y), f2bf(f.z), f2bf(f.w));
    }
    return;
  }
  __shared__ float tile[32][33];
  const int zz = z - 2;
  const float* in = zz == 0 ? W0 : zz == 1 ? W1 : zz == 2 ? W2 : W3;
  ushort* out = zz == 0 ? O0 : zz == 1 ? O1 : zz == 2 ? O2 : O3;
  const float scale = zz == 0 ? QSCALE : 1.0f;
  const int n0 = blockIdx.x * 32, k0 = blockIdx.y * 32;
#pragma unroll
  for (int i = 0; i < 4; ++i)
    tile[ty + i * 8][tx] = in[(size_t)(k0 + ty + i * 8) * DMODEL + n0 + tx];
  __syncthreads();
#pragma unroll
  for (int i = 0; i < 4; ++i)
    out[(size_t)(n0 + ty + i * 8) * DMODEL + k0 + tx] =
        f2bf(tile[tx][ty + i * 8] * scale);
}

// ---------------------------------------------------------------------------
// Fused Q/K/V projection GEMM, global_load_lds(16B) staging, XOR-swizzled on
// the GLOBAL side. 128x128 tile, BK=64, 4 waves. Q/K epilogues write plain
// row-major [4096][1024] bf16 (consumed directly by flash 32x32 fragments);
// V epilogue writes V^T [bh][64][SEQ].
// ---------------------------------------------------------------------------
__global__ __launch_bounds__(256) void mfma_gemm_qkv(
    const ushort* __restrict__ pb, const ushort* __restrict__ xb,
    const ushort* __restrict__ wqt, const ushort* __restrict__ wkt,
    const ushort* __restrict__ wvt, ushort* __restrict__ qws,
    ushort* __restrict__ kws, ushort* __restrict__ vws) {
  __shared__ __align__(16) ushort As[128 * 64];
  __shared__ __align__(16) ushort Bs[128 * 64];
  const int z = blockIdx.z;
  const ushort* A = (z == 0) ? pb : xb;
  const ushort* Bt = (z == 0) ? wqt : (z == 1) ? wkt : wvt;

  const int t = threadIdx.x;
  const int w = t >> 6, lane = t & 63, ln = lane & 15, q = lane >> 4;
  const int wm = w & 1, wn = w >> 1;
  const int row0 = blockIdx.y * 128, col0 = blockIdx.x * 128;
  const int sw = ln & 7;

  f32x4 acc[4][4];
#pragma unroll
  for (int i = 0; i < 4; ++i)
#pragma unroll
    for (int j = 0; j < 4; ++j) acc[i][j] = (f32x4){0.f, 0.f, 0.f, 0.f};

  for (int k0 = 0; k0 < DMODEL; k0 += 64) {
    __syncthreads();  // prior frag reads done
#pragma unroll
    for (int rep = 0; rep < 4; ++rep) {
      const int u0 = rep * 256 + w * 64;
      const int u = u0 + lane;
      const int r = u >> 3, gl = (u & 7) ^ (r & 7);
      gld16(&A[(size_t)(row0 + r) * DMODEL + k0 + gl * 8], &As[u0 * 8]);
      gld16(&Bt[(size_t)(col0 + r) * DMODEL + k0 + gl * 8], &Bs[u0 * 8]);
    }
    __syncthreads();  // vmcnt drain
#pragma unroll
    for (int ks = 0; ks < 2; ++ks) {
      short8 af[4], bf[4];
#pragma unroll
      for (int rt = 0; rt < 4; ++rt)
        af[rt] = *(const short8*)&As[(wm * 64 + rt * 16 + ln) * 64 +
                                     (((ks * 4 + q) ^ sw) * 8)];
#pragma unroll
      for (int ct = 0; ct < 4; ++ct)
        bf[ct] = *(const short8*)&Bs[(wn * 64 + ct * 16 + ln) * 64 +
                                     (((ks * 4 + q) ^ sw) * 8)];
#pragma unroll
      for (int rt = 0; rt < 4; ++rt)
#pragma unroll
        for (int ct = 0; ct < 4; ++ct)
          acc[rt][ct] = __builtin_amdgcn_mfma_f32_16x16x32_bf16(af[rt], bf[ct],
                                                                acc[rt][ct], 0, 0, 0);
    }
  }

  if (z < 2) {
    ushort* dst = z == 0 ? qws : kws;  // row-major [4096][1024]
#pragma unroll
    for (int rt = 0; rt < 4; ++rt)
#pragma unroll
      for (int ct = 0; ct < 4; ++ct) {
        const int c = col0 + wn * 64 + ct * 16 + ln;
#pragma unroll
        for (int reg = 0; reg < 4; ++reg) {
          const int r = row0 + wm * 64 + rt * 16 + q * 4 + reg;
          dst[(size_t)r * DMODEL + c] = f2bf(acc[rt][ct][reg]);
        }
      }
  } else {
    // V^T: vws[bh][64][SEQ]
#pragma unroll
    for (int rt = 0; rt < 4; ++rt)
#pragma unroll
      for (int ct = 0; ct < 4; ++ct) {
        const int c = col0 + wn * 64 + ct * 16 + ln;
        const int hh = c >> 6, d = c & 63;
        const int r0 = row0 + wm * 64 + rt * 16 + q * 4;
        const int bb = r0 >> 11, s0 = r0 & (SEQ - 1);
        ushort4 u4 = make_ushort4(f2bf(acc[rt][ct][0]), f2bf(acc[rt][ct][1]),
                                  f2bf(acc[rt][ct][2]), f2bf(acc[rt][ct][3]));
        *(ushort4*)&vws[((size_t)(bb * HEADS + hh) * DH + d) * SEQ + s0] = u4;
      }
  }
}

// ---------------------------------------------------------------------------
// Flash attention v11: the PROVEN v6 strip structure (each wave owns 32 q x
// the full 64-key tile; 32x32x16 MFMAs, swapped QK^T, in-register softmax
// via cvt_pk+permlane32_swap, 2-buffer DMA, one __syncthreads/iter; passed
// rounds 2/4/6) plus an OPTIONAL key-axis split (SPLIT: blockIdx.z in {0,1},
// each block sweeps 1024 keys). No cross-wave reduction, no LDS aliasing --
// the SPLIT epilogue just dumps unnormalized fp32 acc_o + per-column l.
// Rationale: flash is grid-limited (512 blocks = 2/CU; all pipes <65% busy);
// z=2 doubles co-resident blocks at IDENTICAL total LDS traffic -> approach
// the ~29us LDS-pipe floor. LDS 32 KB -> 4 blocks/CU at launch_bounds(,4);
// v6 VGPR=76 < 128 cap -> no spill.
// ---------------------------------------------------------------------------
template <bool SPLIT>
__global__ __launch_bounds__(256, 4) void flash_mfma_t(
    const ushort* __restrict__ Qg, const ushort* __restrict__ Kg,
    const ushort* __restrict__ Vg, ushort* __restrict__ Og,
    float* __restrict__ Op, float* __restrict__ lp) {
  __shared__ __align__(16) ushort Kst[2][64 * 64];  // 2 x 8 KB, rows = key
  __shared__ __align__(16) ushort Vst[2][64 * 64];  // 2 x 8 KB, rows = d

  const int t = threadIdx.x;
  const int w = t >> 6, lane = t & 63;
  const int l31 = lane & 31, hi = lane >> 5, l7 = lane & 7, l8 = lane >> 3;
  const int bh = blockIdx.x;  // 0..31 (XCD-pinning: id%8 = bh%8)
  const int qt = blockIdx.y;  // 0..15 (128-row Q tile)
  const int b = bh >> 4, h = bh & 15;
  const int NKT = SPLIT ? 16 : 32;
  const int kt0 = SPLIT ? ((int)blockIdx.z * 16) : 0;

  const ushort* qrow = Qg + ((size_t)b * SEQ) * DMODEL + h * DH;  // [s][1024]
  const ushort* krow = Kg + ((size_t)b * SEQ) * DMODEL + h * DH;
  const ushort* vg = Vg + (size_t)bh * DH * SEQ;                  // [64][SEQ]

  // Q B-fragments: lane: qcol = l31, k = ks*16 + hi*8 + j  (row-major read)
  short8 qf[4];
#pragma unroll
  for (int ks = 0; ks < 4; ++ks)
    qf[ks] = *(const short8*)
        &qrow[(size_t)(qt * 128 + w * 32 + l31) * DMODEL + ks * 16 + hi * 8];

  f32x16 acc_o[2];
#pragma unroll
  for (int db = 0; db < 2; ++db)
#pragma unroll
    for (int e = 0; e < 16; ++e) acc_o[db][e] = 0.f;
  float l_i = 0.f;

  // DMA assignment: w0: K f0-3, w1: K f4-7, w2: V f0-3, w3: V f4-7.
  // frag f = 8 rows x 64 cols; lane: row f*8+l8, 16B chunk (l7^l8)
  // (global-side XOR swizzle; LDS dest linear).
  const int fbase = (w & 1) * 4;
  const bool isV = (w >= 2);
  const int swz = (l7 ^ l8) * 8;

  auto stage = [&](int kt, int buf) {
#pragma unroll
    for (int i = 0; i < 4; ++i) {
      const int f = fbase + i;
      if (!isV)
        gld16(&krow[(size_t)(kt * 64 + f * 8 + l8) * DMODEL + swz],
              &Kst[buf][f * 512]);
      else
        gld16(&vg[(size_t)(f * 8 + l8) * SEQ + kt * 64 + swz],
              &Vst[buf][f * 512]);
    }
  };

  stage(kt0, 0);
  __syncthreads();  // prologue DMA drained

  for (int i = 0; i < NKT; ++i) {
    const int kt = kt0 + i, cur = i & 1;
    if (i + 1 < NKT) stage(kt + 1, cur ^ 1);

    const ushort* Kc = &Kst[cur][0];
    const ushort* Vc = &Vst[cur][0];

    // S^T = K-tile @ Q^T : accs[kb] covers keys kb*32..+31 x 32 q-cols
    f32x16 accs[2];
#pragma unroll
    for (int kb = 0; kb < 2; ++kb)
#pragma unroll
      for (int e = 0; e < 16; ++e) accs[kb][e] = 0.f;
#pragma unroll
    for (int kb = 0; kb < 2; ++kb)
#pragma unroll
      for (int ks = 0; ks < 4; ++ks) {
        const short8 kf = *(const short8*)
            &Kc[(kb * 32 + l31) * 64 + (((ks * 2 + hi) ^ l7) * 8)];
        accs[kb] = __builtin_amdgcn_mfma_f32_32x32x16_bf16(kf, qf[ks],
                                                           accs[kb], 0, 0, 0);
      }

    // hoist V fragment reads; ds latency hides under softmax VALU below
    short8 vf[4][2];
#pragma unroll
    for (int sg = 0; sg < 4; ++sg)
#pragma unroll
      for (int db = 0; db < 2; ++db)
        vf[sg][db] = *(const short8*)
            &Vc[(db * 32 + l31) * 64 + (((sg * 2 + hi) ^ l7) * 8)];

    // p = 2^s (Q pre-scaled); lane-partial l (lane owns q-column l31)
#pragma unroll
    for (int kb = 0; kb < 2; ++kb)
#pragma unroll
      for (int e = 0; e < 16; ++e) {
        const float p = __builtin_amdgcn_exp2f(accs[kb][e]);
        accs[kb][e] = p;
        l_i += p;
      }

    // in-register pack + lane-half exchange -> PV A-fragments pa[4]
    // lane holds k = 8o + 4hi + 2u (+1) in word wq[o][u]; slice sl needs
    // k = 16sl + 8hi + j: (word0,word2)=swap(wq[2sl][0], wq[2sl+1][0]),
    //                     (word1,word3)=swap(wq[2sl][1], wq[2sl+1][1])
    short8 pa[4];
#pragma unroll
    for (int kb = 0; kb < 2; ++kb) {
      unsigned wq[4][2];
#pragma unroll
      for (int o = 0; o < 4; ++o) {
        asm("v_cvt_pk_bf16_f32 %0, %1, %2"
            : "=v"(wq[o][0])
            : "v"(accs[kb][4 * o + 0]), "v"(accs[kb][4 * o + 1]));
        asm("v_cvt_pk_bf16_f32 %0, %1, %2"
            : "=v"(wq[o][1])
            : "v"(accs[kb][4 * o + 2]), "v"(accs[kb][4 * o + 3]));
      }
#pragma unroll
      for (int sl = 0; sl < 2; ++sl) {
        uint2v r02 = __builtin_amdgcn_permlane32_swap(wq[2 * sl][0],
                                                      wq[2 * sl + 1][0],
                                                      false, false);
        uint2v r13 = __builtin_amdgcn_permlane32_swap(wq[2 * sl][1],
                                                      wq[2 * sl + 1][1],
                                                      false, false);
        uint4v pk = {r02.x, r13.x, r02.y, r13.y};
        pa[kb * 2 + sl] = __builtin_bit_cast(short8, pk);
      }
    }

    // O += P @ V
#pragma unroll
    for (int sg = 0; sg < 4; ++sg)
#pragma unroll
      for (int db = 0; db < 2; ++db)
        acc_o[db] = __builtin_amdgcn_mfma_f32_32x32x16_bf16(
            pa[sg], vf[sg][db], acc_o[db], 0, 0, 0);

    __syncthreads();  // reads of [cur] done + next DMA drained
  }

  // epilogue: complete l over both lane halves
  l_i += __shfl_xor(l_i, 32);

  if (SPLIT) {
    // dump unnormalized fp32 O-partial + per-column l-partial
    float* Ops = Op + (size_t)blockIdx.z * 2 * SEQ * DMODEL;
#pragma unroll
    for (int o = 0; o < 4; ++o)
#pragma unroll
      for (int r0 = 0; r0 < 4; ++r0) {
        const int row = o * 8 + r0 + 4 * hi;           // q-row of reg e=4o+r0
        const int s = qt * 128 + w * 32 + row;
#pragma unroll
        for (int db = 0; db < 2; ++db)
          Ops[((size_t)b * SEQ + s) * DMODEL + h * DH + db * 32 + l31] =
              acc_o[db][4 * o + r0];
      }
    if (hi == 0)
      lp[((size_t)blockIdx.z * 32 + bh) * SEQ + qt * 128 + w * 32 + l31] = l_i;
  } else {
    const float inv = 1.0f / l_i;  // for q-column l31 (both halves hold it)
#pragma unroll
    for (int o = 0; o < 4; ++o)
#pragma unroll
      for (int r0 = 0; r0 < 4; ++r0) {
        const int row = o * 8 + r0 + 4 * hi;
        const float invr = __shfl(inv, row, 64);       // lane 'row' holds it
        const int s = qt * 128 + w * 32 + row;
#pragma unroll
        for (int db = 0; db < 2; ++db)
          Og[(size_t)(b * SEQ + s) * DMODEL + h * DH + db * 32 + l31] =
              f2bf(acc_o[db][4 * o + r0] * invr);
      }
  }
}

// ---------------------------------------------------------------------------
// Merge the two K-split partials: aws = bf16((O0+O1) / (l0+l1)).
// 4096x1024 fp32 x2 read + bf16 write ~ 40 MB -> HBM-bound, ~7 us.
// ---------------------------------------------------------------------------
__global__ __launch_bounds__(256) void merge_o(const float* __restrict__ Op,
                                               const float* __restrict__ lp,
                                               ushort* __restrict__ aws) {
  const int row = blockIdx.x;           // 0..4095  (= b*SEQ + s)
  const int c = threadIdx.x * 4;        // 0..1020
  const int b_ = row >> 11, s = row & 2047, h = c >> 6;
  const float lsum = lp[(b_ * 16 + h) * SEQ + s] +
                     lp[(size_t)32 * SEQ + (b_ * 16 + h) * SEQ + s];
  const float inv = 1.0f / lsum;
  const float4 o0 = *(const float4*)&Op[(size_t)row * DMODEL + c];
  const float4 o1 =
      *(const float4*)&Op[(size_t)2 * SEQ * DMODEL + (size_t)row * DMODEL + c];
  ushort4 u = make_ushort4(
      f2bf((o0.x + o1.x) * inv), f2bf((o0.y + o1.y) * inv),
      f2bf((o0.z + o1.z) * inv), f2bf((o0.w + o1.w) * inv));
  *(ushort4*)&aws[(size_t)row * DMODEL + c] = u;
}

// ---------------------------------------------------------------------------
// Output projection: out = aws[4096,1024] @ WoT^T + bo (fp32). 64x128 tile,
// BK=64, global_load_lds staging, 512 blocks.
// ---------------------------------------------------------------------------
__global__ __launch_bounds__(256) void mfma_gemm_out(const ushort* __restrict__ A,
                                                     const ushort* __restrict__ Bt,
                                                     const float* __restrict__ bias,
                                                     float* __restrict__ dst) {
  __shared__ __align__(16) ushort As[64 * 64];
  __shared__ __align__(16) ushort Bs[128 * 64];
  const int t = threadIdx.x;
  const int w = t >> 6, lane = t & 63, ln = lane & 15, q = lane >> 4;
  const int wm = w & 1, wn = w >> 1;
  const int row0 = blockIdx.y * 64, col0 = blockIdx.x * 128;
  const int sw = ln & 7;

  f32x4 acc[2][4];
#pragma unroll
  for (int i = 0; i < 2; ++i)
#pragma unroll
    for (int j = 0; j < 4; ++j) acc[i][j] = (f32x4){0.f, 0.f, 0.f, 0.f};

  for (int k0 = 0; k0 < DMODEL; k0 += 64) {
    __syncthreads();
#pragma unroll
    for (int rep = 0; rep < 2; ++rep) {
      const int u0 = rep * 256 + w * 64;
      const int u = u0 + lane;
      const int r = u >> 3, gl = (u & 7) ^ (r & 7);
      gld16(&A[(size_t)(row0 + r) * DMODEL + k0 + gl * 8], &As[u0 * 8]);
    }
#pragma unroll
    for (int rep = 0; rep < 4; ++rep) {
      const int u0 = rep * 256 + w * 64;
      const int u = u0 + lane;
      const int r = u >> 3, gl = (u & 7) ^ (r & 7);
      gld16(&Bt[(size_t)(col0 + r) * DMODEL + k0 + gl * 8], &Bs[u0 * 8]);
    }
    __syncthreads();
#pragma unroll
    for (int ks = 0; ks < 2; ++ks) {
      short8 af[2], bf[4];
#pragma unroll
      for (int rt = 0; rt < 2; ++rt)
        af[rt] = *(const short8*)&As[(wm * 32 + rt * 16 + ln) * 64 +
                                     (((ks * 4 + q) ^ sw) * 8)];
#pragma unroll
      for (int ct = 0; ct < 4; ++ct)
        bf[ct] = *(const short8*)&Bs[(wn * 64 + ct * 16 + ln) * 64 +
                                     (((ks * 4 + q) ^ sw) * 8)];
#pragma unroll
      for (int rt = 0; rt < 2; ++rt)
#pragma unroll
        for (int ct = 0; ct < 4; ++ct)
          acc[rt][ct] = __builtin_amdgcn_mfma_f32_16x16x32_bf16(af[rt], bf[ct],
                                                                acc[rt][ct], 0, 0, 0);
    }
  }

#pragma unroll
  for (int rt = 0; rt < 2; ++rt)
#pragma unroll
    for (int ct = 0; ct < 4; ++ct) {
      const int c = col0 + wn * 64 + ct * 16 + ln;
      const float bi = bias[c];
#pragma unroll
      for (int reg = 0; reg < 4; ++reg) {
        const int r = row0 + wm * 32 + rt * 16 + q * 4 + reg;
        dst[(size_t)r * DMODEL + c] = acc[rt][ct][reg] + bi;
      }
    }
}

extern "C" void kernel_launch(void* const* d_in, const int* in_sizes, int n_in,
                              void* d_out, int out_size, void* d_ws,
                              size_t ws_size, hipStream_t stream) {
  const float* patch = (const float*)d_in[0];
  const float* pixel = (const float*)d_in[1];
  const float* Wq = (const float*)d_in[2];
  const float* Wk = (const float*)d_in[3];
  const float* Wv = (const float*)d_in[4];
  const float* Wo = (const float*)d_in[5];
  const float* bo = (const float*)d_in[6];
  float* out = (float*)d_out;

  const size_t E = (size_t)2 * SEQ * DMODEL;  // 4,194,304
  const size_t W = (size_t)DMODEL * DMODEL;   // 1,048,576
  ushort* pb  = (ushort*)d_ws;      // patch bf16
  ushort* xb  = pb + E;             // pixel bf16
  ushort* wqt = xb + E;             // Wq^T * QSCALE bf16 [N][K]
  ushort* wkt = wqt + W;
  ushort* wvt = wkt + W;
  ushort* wot = wvt + W;            // live until mfma_gemm_out
  ushort* qws = wot + W;            // Q row-major [4096][1024] bf16
  ushort* kws = qws + E;            // K row-major [4096][1024] bf16
  ushort* vws = kws + E;            // V^T [bh][64][SEQ] bf16
  ushort* aws = vws + E;            // [4096][1024] row-major bf16
  // K-split partials live past aws (used only if ws is large enough):
  // Opart fp32 [2][4096][1024] (32 MB) + lpart fp32 [2][32][2048] (512 KB)
  const size_t base_ush = (size_t)6 * E + 4 * W;  // 29,360,128 ushorts
  float* Opart = (float*)(pb + base_ush);
  float* lpart = Opart + (size_t)2 * 2 * SEQ * DMODEL;
  const size_t need_bytes =
      base_ush * 2 + ((size_t)2 * 2 * SEQ * DMODEL + 2 * 32 * SEQ) * 4;

  prologue<<<dim3(32, 32, 6), dim3(32, 8), 0, stream>>>(
      patch, pixel, Wq, Wk, Wv, Wo, pb, xb, wqt, wkt, wvt, wot);
  mfma_gemm_qkv<<<dim3(8, 32, 3), 256, 0, stream>>>(pb, xb, wqt, wkt, wvt,
                                                    qws, kws, vws);
  if (ws_size >= need_bytes) {
    flash_mfma_t<true><<<dim3(32, 16, 2), 256, 0, stream>>>(
        qws, kws, vws, nullptr, Opart, lpart);
    merge_o<<<4096, 256, 0, stream>>>(Opart, lpart, aws);
  } else {
    flash_mfma_t<false><<<dim3(32, 16, 1), 256, 0, stream>>>(
        qws, kws, vws, aws, nullptr, nullptr);
  }
  mfma_gemm_out<<<dim3(8, 64), 256, 0, stream>>>(aws, wot, bo, out);
}

// Round 10
// 203.192 us; speedup vs baseline: 1.0855x; 1.0855x over previous
//
#include <hip/hip_runtime.h>

#define SEQ 2048
#define DMODEL 1024
#define HEADS 16
#define DH 64
// fold (1/sqrt(64)) * log2(e) into Wq so scores arrive in exp2 domain
#define QSCALE 0.180336880f

typedef __attribute__((ext_vector_type(8))) short short8;
typedef __attribute__((ext_vector_type(4))) float f32x4;
typedef __attribute__((ext_vector_type(16))) float f32x16;
typedef __attribute__((ext_vector_type(2))) unsigned int uint2v;
typedef __attribute__((ext_vector_type(4))) unsigned int uint4v;

__device__ __forceinline__ ushort f2bf(float x) {
  union { float f; unsigned u; } v; v.f = x;
  return (ushort)((v.u + 0x7fffu + ((v.u >> 16) & 1u)) >> 16);
}

// async global->LDS, 16B per lane. LDS dest = wave-uniform base + lane*16.
__device__ __forceinline__ void gld16(const ushort* g, ushort* l) {
  __builtin_amdgcn_global_load_lds(
      (const __attribute__((address_space(1))) unsigned int*)g,
      (__attribute__((address_space(3))) unsigned int*)l, 16, 0, 0);
}

// ---------------------------------------------------------------------------
// Fused prologue. z=0/1: fp32->bf16 cast of patch/pixel (4x float4/thread).
// z=2..5: transpose-cast Wq*QSCALE / Wk / Wv / Wo to [N][K] bf16.
// ---------------------------------------------------------------------------
__global__ __launch_bounds__(256) void prologue(
    const float* __restrict__ patch, const float* __restrict__ pixel,
    const float* __restrict__ W0, const float* __restrict__ W1,
    const float* __restrict__ W2, const float* __restrict__ W3,
    ushort* __restrict__ pb, ushort* __restrict__ xb,
    ushort* __restrict__ O0, ushort* __restrict__ O1,
    ushort* __restrict__ O2, ushort* __restrict__ O3) {
  const int z = blockIdx.z;
  const int tx = threadIdx.x, ty = threadIdx.y;
  if (z < 2) {
    const float4* in = (const float4*)(z ? pixel : patch);
    ushort4* out = (ushort4*)(z ? xb : pb);
    const int base = (blockIdx.y * 32 + blockIdx.x) * 256 + ty * 32 + tx;
#pragma unroll
    for (int rep = 0; rep < 4; ++rep) {
      const int i = base + rep * 262144;
      float4 f = in[i];
      out[i] = make_ushort4(f2bf(f.x), f2bf(f.y), f2bf(f.z), f2bf(f.w));
    }
    return;
  }
  __shared__ float tile[32][33];
  const int zz = z - 2;
  const float* in = zz == 0 ? W0 : zz == 1 ? W1 : zz == 2 ? W2 : W3;
  ushort* out = zz == 0 ? O0 : zz == 1 ? O1 : zz == 2 ? O2 : O3;
  const float scale = zz == 0 ? QSCALE : 1.0f;
  const int n0 = blockIdx.x * 32, k0 = blockIdx.y * 32;
#pragma unroll
  for (int i = 0; i < 4; ++i)
    tile[ty + i * 8][tx] = in[(size_t)(k0 + ty + i * 8) * DMODEL + n0 + tx];
  __syncthreads();
#pragma unroll
  for (int i = 0; i < 4; ++i)
    out[(size_t)(n0 + ty + i * 8) * DMODEL + k0 + tx] =
        f2bf(tile[tx][ty + i * 8] * scale);
}

// ---------------------------------------------------------------------------
// Fused Q/K/V projection GEMM, global_load_lds(16B) staging, XOR-swizzled on
// the GLOBAL side. 128x128 tile, BK=64, 4 waves. Q/K epilogues restage acc
// through the (dead) 32 KB staging LDS with an XOR swizzle, then store 16B
// short8 coalesced (was: 64 scalar 2B stores/thread). V writes V^T ushort4.
// ---------------------------------------------------------------------------
__global__ __launch_bounds__(256) void mfma_gemm_qkv(
    const ushort* __restrict__ pb, const ushort* __restrict__ xb,
    const ushort* __restrict__ wqt, const ushort* __restrict__ wkt,
    const ushort* __restrict__ wvt, ushort* __restrict__ qws,
    ushort* __restrict__ kws, ushort* __restrict__ vws) {
  __shared__ __align__(16) ushort Sh[128 * 128];  // 32 KB: As|Bs, then restage
  ushort* As = Sh;
  ushort* Bs = Sh + 128 * 64;
  const int z = blockIdx.z;
  const ushort* A = (z == 0) ? pb : xb;
  const ushort* Bt = (z == 0) ? wqt : (z == 1) ? wkt : wvt;

  const int t = threadIdx.x;
  const int w = t >> 6, lane = t & 63, ln = lane & 15, q = lane >> 4;
  const int wm = w & 1, wn = w >> 1;
  const int row0 = blockIdx.y * 128, col0 = blockIdx.x * 128;
  const int sw = ln & 7;

  f32x4 acc[4][4];
#pragma unroll
  for (int i = 0; i < 4; ++i)
#pragma unroll
    for (int j = 0; j < 4; ++j) acc[i][j] = (f32x4){0.f, 0.f, 0.f, 0.f};

  for (int k0 = 0; k0 < DMODEL; k0 += 64) {
    __syncthreads();  // prior frag reads done
#pragma unroll
    for (int rep = 0; rep < 4; ++rep) {
      const int u0 = rep * 256 + w * 64;
      const int u = u0 + lane;
      const int r = u >> 3, gl = (u & 7) ^ (r & 7);
      gld16(&A[(size_t)(row0 + r) * DMODEL + k0 + gl * 8], &As[u0 * 8]);
      gld16(&Bt[(size_t)(col0 + r) * DMODEL + k0 + gl * 8], &Bs[u0 * 8]);
    }
    __syncthreads();  // vmcnt drain
#pragma unroll
    for (int ks = 0; ks < 2; ++ks) {
      short8 af[4], bf[4];
#pragma unroll
      for (int rt = 0; rt < 4; ++rt)
        af[rt] = *(const short8*)&As[(wm * 64 + rt * 16 + ln) * 64 +
                                     (((ks * 4 + q) ^ sw) * 8)];
#pragma unroll
      for (int ct = 0; ct < 4; ++ct)
        bf[ct] = *(const short8*)&Bs[(wn * 64 + ct * 16 + ln) * 64 +
                                     (((ks * 4 + q) ^ sw) * 8)];
#pragma unroll
      for (int rt = 0; rt < 4; ++rt)
#pragma unroll
        for (int ct = 0; ct < 4; ++ct)
          acc[rt][ct] = __builtin_amdgcn_mfma_f32_16x16x32_bf16(af[rt], bf[ct],
                                                                acc[rt][ct], 0, 0, 0);
    }
  }

  if (z < 2) {
    ushort* dst = z == 0 ? qws : kws;  // row-major [4096][1024]
    __syncthreads();  // all waves done reading As/Bs before overwrite
    // restage: bf16 into Sh[rl][cl ^ ((rl&7)*8)]  (write ~4-way, read free)
#pragma unroll
    for (int rt = 0; rt < 4; ++rt)
#pragma unroll
      for (int ct = 0; ct < 4; ++ct) {
        const int cl = wn * 64 + ct * 16 + ln;
#pragma unroll
        for (int reg = 0; reg < 4; ++reg) {
          const int rl = wm * 64 + rt * 16 + q * 4 + reg;
          Sh[rl * 128 + (cl ^ ((rl & 7) * 8))] = f2bf(acc[rt][ct][reg]);
        }
      }
    __syncthreads();
    // readback: 128 rows x 16 chunks(8 ushorts); 8 chunks/thread, 16B stores
#pragma unroll
    for (int i = 0; i < 8; ++i) {
      const int chunk = i * 256 + t;
      const int rl = chunk >> 4, m = chunk & 15;
      const short8 v8 =
          *(const short8*)&Sh[rl * 128 + ((m * 8) ^ ((rl & 7) * 8))];
      *(short8*)&dst[(size_t)(row0 + rl) * DMODEL + col0 + m * 8] = v8;
    }
  } else {
    // V^T: vws[bh][64][SEQ]  (already 8B-vectorized along s)
#pragma unroll
    for (int rt = 0; rt < 4; ++rt)
#pragma unroll
      for (int ct = 0; ct < 4; ++ct) {
        const int c = col0 + wn * 64 + ct * 16 + ln;
        const int hh = c >> 6, d = c & 63;
        const int r0 = row0 + wm * 64 + rt * 16 + q * 4;
        const int bb = r0 >> 11, s0 = r0 & (SEQ - 1);
        ushort4 u4 = make_ushort4(f2bf(acc[rt][ct][0]), f2bf(acc[rt][ct][1]),
                                  f2bf(acc[rt][ct][2]), f2bf(acc[rt][ct][3]));
        *(ushort4*)&vws[((size_t)(bb * HEADS + hh) * DH + d) * SEQ + s0] = u4;
      }
  }
}

// ---------------------------------------------------------------------------
// Flash attention v9 (round-6 EXACT, proven 45.9us): dual-stream dep-chain
// break -- each barrier region processes TWO K-tiles as independent register
// streams (A, B); scheduler fills A's softmax window with B's MFMA issue.
// 32x32x16, swapped QK^T, in-register softmax via cvt_pk+permlane32_swap,
// 2-buffer DMA, one __syncthreads per region. l_i as 4 partials.
// ---------------------------------------------------------------------------
__global__ __launch_bounds__(256, 2) void flash_mfma(
    const ushort* __restrict__ Qg, const ushort* __restrict__ Kg,
    const ushort* __restrict__ Vg, ushort* __restrict__ Og) {
  __shared__ __align__(16) ushort Kst[2][2][64 * 64];  // [buf][sub] 8 KB each
  __shared__ __align__(16) ushort Vst[2][2][64 * 64];

  const int t = threadIdx.x;
  const int w = t >> 6, lane = t & 63;
  const int l31 = lane & 31, hi = lane >> 5, l7 = lane & 7, l8 = lane >> 3;
  const int bh = blockIdx.x;  // 0..31 (XCD-pinning: id%8 = bh%8)
  const int qt = blockIdx.y;  // 0..15 (128-row Q tile)
  const int b = bh >> 4, h = bh & 15;

  const ushort* qrow = Qg + ((size_t)b * SEQ) * DMODEL + h * DH;  // [s][1024]
  const ushort* krow = Kg + ((size_t)b * SEQ) * DMODEL + h * DH;
  const ushort* vg = Vg + (size_t)bh * DH * SEQ;                  // [64][SEQ]

  // Q B-fragments: lane: qcol = l31, k = ks*16 + hi*8 + j  (row-major read)
  short8 qf[4];
#pragma unroll
  for (int ks = 0; ks < 4; ++ks)
    qf[ks] = *(const short8*)
        &qrow[(size_t)(qt * 128 + w * 32 + l31) * DMODEL + ks * 16 + hi * 8];

  f32x16 acc_o[2];
#pragma unroll
  for (int db = 0; db < 2; ++db)
#pragma unroll
    for (int e = 0; e < 16; ++e) acc_o[db][e] = 0.f;
  float l4[4] = {0.f, 0.f, 0.f, 0.f};

  // DMA assignment: w0: K f0-3, w1: K f4-7, w2: V f0-3, w3: V f4-7.
  // frag f covers 8 rows x 64 cols; lane: row f*8+l8, 16B chunk (l7^l8)
  // (global-side XOR swizzle; LDS dest is linear).
  const int fbase = (w & 1) * 4;
  const bool isV = (w >= 2);
  const int swz = (l7 ^ l8) * 8;

  auto stagePair = [&](int pt, int buf) {
#pragma unroll
    for (int st2 = 0; st2 < 2; ++st2) {
      const int tile = pt * 2 + st2;
#pragma unroll
      for (int i = 0; i < 4; ++i) {
        const int f = fbase + i;
        if (!isV)
          gld16(&krow[(size_t)(tile * 64 + f * 8 + l8) * DMODEL + swz],
                &Kst[buf][st2][f * 512]);
        else
          gld16(&vg[(size_t)(f * 8 + l8) * SEQ + tile * 64 + swz],
                &Vst[buf][st2][f * 512]);
      }
    }
  };

  stagePair(0, 0);
  __syncthreads();  // prologue DMA drained

  for (int pt = 0; pt < SEQ / 128; ++pt) {
    const int cur = pt & 1;
    // issue NEXT pair's DMA first (lands during this region's compute)
    if (pt + 1 < SEQ / 128) stagePair(pt + 1, cur ^ 1);

    const ushort* KcA = &Kst[cur][0][0];
    const ushort* KcB = &Kst[cur][1][0];
    const ushort* VcA = &Vst[cur][0][0];
    const ushort* VcB = &Vst[cur][1][0];

    // ---- QK^T for both streams (independent MFMA chains) ----
    f32x16 accsA[2], accsB[2];
#pragma unroll
    for (int kb = 0; kb < 2; ++kb)
#pragma unroll
      for (int e = 0; e < 16; ++e) {
        accsA[kb][e] = 0.f;
        accsB[kb][e] = 0.f;
      }
#pragma unroll
    for (int kb = 0; kb < 2; ++kb)
#pragma unroll
      for (int ks = 0; ks < 4; ++ks) {
        const int off = (kb * 32 + l31) * 64 + (((ks * 2 + hi) ^ l7) * 8);
        const short8 kfA = *(const short8*)&KcA[off];
        accsA[kb] = __builtin_amdgcn_mfma_f32_32x32x16_bf16(kfA, qf[ks],
                                                            accsA[kb], 0, 0, 0);
        const short8 kfB = *(const short8*)&KcB[off];
        accsB[kb] = __builtin_amdgcn_mfma_f32_32x32x16_bf16(kfB, qf[ks],
                                                            accsB[kb], 0, 0, 0);
      }

    // hoist stream A's V fragments
    short8 vfA[4][2];
#pragma unroll
    for (int sg = 0; sg < 4; ++sg)
#pragma unroll
      for (int db = 0; db < 2; ++db)
        vfA[sg][db] = *(const short8*)
            &VcA[(db * 32 + l31) * 64 + (((sg * 2 + hi) ^ l7) * 8)];

// softmax (exp2 in the pre-scaled domain) + in-register pack/permlane ->
// PV A-fragments. lane holds k = 8o + 4hi + 2u (+1) in word wq[o][u];
// slice sl needs k = 16sl + 8hi + j:
//   (word0,word2)=swap(wq[2sl][0], wq[2sl+1][0])
//   (word1,word3)=swap(wq[2sl][1], wq[2sl+1][1])
#define SOFTMAX_PACK(ACCS, PA)                                               \
  {                                                                          \
    _Pragma("unroll") for (int kb = 0; kb < 2; ++kb)                         \
        _Pragma("unroll") for (int e = 0; e < 16; ++e) {                     \
      const float p = __builtin_amdgcn_exp2f(ACCS[kb][e]);                   \
      ACCS[kb][e] = p;                                                       \
      l4[e & 3] += p;                                                        \
    }                                                                        \
    _Pragma("unroll") for (int kb = 0; kb < 2; ++kb) {                       \
      unsigned wq[4][2];                                                     \
      _Pragma("unroll") for (int o = 0; o < 4; ++o) {                        \
        asm("v_cvt_pk_bf16_f32 %0, %1, %2"                                   \
            : "=v"(wq[o][0])                                                 \
            : "v"(ACCS[kb][4 * o + 0]), "v"(ACCS[kb][4 * o + 1]));           \
        asm("v_cvt_pk_bf16_f32 %0, %1, %2"                                   \
            : "=v"(wq[o][1])                                                 \
            : "v"(ACCS[kb][4 * o + 2]), "v"(ACCS[kb][4 * o + 3]));           \
      }                                                                      \
      _Pragma("unroll") for (int sl = 0; sl < 2; ++sl) {                     \
        uint2v r02 = __builtin_amdgcn_permlane32_swap(                       \
            wq[2 * sl][0], wq[2 * sl + 1][0], false, false);                 \
        uint2v r13 = __builtin_amdgcn_permlane32_swap(                       \
            wq[2 * sl][1], wq[2 * sl + 1][1], false, false);                 \
        uint4v pk = {r02.x, r13.x, r02.y, r13.y};                            \
        PA[kb * 2 + sl] = __builtin_bit_cast(short8, pk);                    \
      }                                                                      \
    }                                                                        \
  }

    short8 paA[4];
    SOFTMAX_PACK(accsA, paA);

    // stream B's V fragments (after A's softmax to bound register pressure)
    short8 vfB[4][2];
#pragma unroll
    for (int sg = 0; sg < 4; ++sg)
#pragma unroll
      for (int db = 0; db < 2; ++db)
        vfB[sg][db] = *(const short8*)
            &VcB[(db * 32 + l31) * 64 + (((sg * 2 + hi) ^ l7) * 8)];

    // O += P_A @ V_A  (overlaps with B's softmax below per scheduler)
#pragma unroll
    for (int sg = 0; sg < 4; ++sg)
#pragma unroll
      for (int db = 0; db < 2; ++db)
        acc_o[db] = __builtin_amdgcn_mfma_f32_32x32x16_bf16(
            paA[sg], vfA[sg][db], acc_o[db], 0, 0, 0);

    short8 paB[4];
    SOFTMAX_PACK(accsB, paB);
#undef SOFTMAX_PACK

    // O += P_B @ V_B
#pragma unroll
    for (int sg = 0; sg < 4; ++sg)
#pragma unroll
      for (int db = 0; db < 2; ++db)
        acc_o[db] = __builtin_amdgcn_mfma_f32_32x32x16_bf16(
            paB[sg], vfB[sg][db], acc_o[db], 0, 0, 0);

    __syncthreads();  // reads of [cur] done + next pair's DMA drained
  }

  // epilogue: complete l over both lane halves, broadcast per output row,
  // normalize, write bf16 row-major [4096][1024]
  float l_i = (l4[0] + l4[1]) + (l4[2] + l4[3]);
  l_i += __shfl_xor(l_i, 32);
  const float inv = 1.0f / l_i;  // for q-column l31 (both halves hold it)
#pragma unroll
  for (int o = 0; o < 4; ++o)
#pragma unroll
    for (int r0 = 0; r0 < 4; ++r0) {
      const int row = o * 8 + r0 + 4 * hi;             // q-row of reg e=4o+r0
      const float invr = __shfl(inv, row, 64);         // lane 'row' holds it
      const int s = qt * 128 + w * 32 + row;
#pragma unroll
      for (int db = 0; db < 2; ++db)
        Og[(size_t)(b * SEQ + s) * DMODEL + h * DH + db * 32 + l31] =
            f2bf(acc_o[db][4 * o + r0] * invr);
    }
}

// ---------------------------------------------------------------------------
// Output projection: out = aws[4096,1024] @ WoT^T + bo (fp32). 64x128 tile,
// BK=64, global_load_lds staging, 512 blocks. Epilogue restages acc through
// a 32 KB swizzled fp32 LDS buffer -> 8 float4 stores/thread (was 32 scalar).
// ---------------------------------------------------------------------------
__global__ __launch_bounds__(256) void mfma_gemm_out(const ushort* __restrict__ A,
                                                     const ushort* __restrict__ Bt,
                                                     const float* __restrict__ bias,
                                                     float* __restrict__ dst) {
  __shared__ __align__(16) ushort As[64 * 64];
  __shared__ __align__(16) ushort Bs[128 * 64];
  __shared__ __align__(16) float Shf[64 * 128];  // 32 KB epilogue restage
  const int t = threadIdx.x;
  const int w = t >> 6, lane = t & 63, ln = lane & 15, q = lane >> 4;
  const int wm = w & 1, wn = w >> 1;
  const int row0 = blockIdx.y * 64, col0 = blockIdx.x * 128;
  const int sw = ln & 7;

  f32x4 acc[2][4];
#pragma unroll
  for (int i = 0; i < 2; ++i)
#pragma unroll
    for (int j = 0; j < 4; ++j) acc[i][j] = (f32x4){0.f, 0.f, 0.f, 0.f};

  for (int k0 = 0; k0 < DMODEL; k0 += 64) {
    __syncthreads();
#pragma unroll
    for (int rep = 0; rep < 2; ++rep) {
      const int u0 = rep * 256 + w * 64;
      const int u = u0 + lane;
      const int r = u >> 3, gl = (u & 7) ^ (r & 7);
      gld16(&A[(size_t)(row0 + r) * DMODEL + k0 + gl * 8], &As[u0 * 8]);
    }
#pragma unroll
    for (int rep = 0; rep < 4; ++rep) {
      const int u0 = rep * 256 + w * 64;
      const int u = u0 + lane;
      const int r = u >> 3, gl = (u & 7) ^ (r & 7);
      gld16(&Bt[(size_t)(col0 + r) * DMODEL + k0 + gl * 8], &Bs[u0 * 8]);
    }
    __syncthreads();
#pragma unroll
    for (int ks = 0; ks < 2; ++ks) {
      short8 af[2], bf[4];
#pragma unroll
      for (int rt = 0; rt < 2; ++rt)
        af[rt] = *(const short8*)&As[(wm * 32 + rt * 16 + ln) * 64 +
                                     (((ks * 4 + q) ^ sw) * 8)];
#pragma unroll
      for (int ct = 0; ct < 4; ++ct)
        bf[ct] = *(const short8*)&Bs[(wn * 64 + ct * 16 + ln) * 64 +
                                     (((ks * 4 + q) ^ sw) * 8)];
#pragma unroll
      for (int rt = 0; rt < 2; ++rt)
#pragma unroll
        for (int ct = 0; ct < 4; ++ct)
          acc[rt][ct] = __builtin_amdgcn_mfma_f32_16x16x32_bf16(af[rt], bf[ct],
                                                                acc[rt][ct], 0, 0, 0);
    }
  }

  // restage epilogue: Shf[rl][cl ^ ((rl&7)*4)], then float4 + bias stores
  __syncthreads();  // all frag reads done (Shf separate, but keep waves synced)
#pragma unroll
  for (int rt = 0; rt < 2; ++rt)
#pragma unroll
    for (int ct = 0; ct < 4; ++ct) {
      const int cl = wn * 64 + ct * 16 + ln;
#pragma unroll
      for (int reg = 0; reg < 4; ++reg) {
        const int rl = wm * 32 + rt * 16 + q * 4 + reg;
        Shf[rl * 128 + (cl ^ ((rl & 7) * 4))] = acc[rt][ct][reg];
      }
    }
  __syncthreads();
#pragma unroll
  for (int i = 0; i < 8; ++i) {
    const int chunk = i * 256 + t;
    const int rl = chunk >> 5, m = chunk & 31;
    const float4 v4 =
        *(const float4*)&Shf[rl * 128 + ((m * 4) ^ ((rl & 7) * 4))];
    const float4 b4 = *(const float4*)&bias[col0 + m * 4];
    float4 o4 = make_float4(v4.x + b4.x, v4.y + b4.y, v4.z + b4.z, v4.w + b4.w);
    *(float4*)&dst[(size_t)(row0 + rl) * DMODEL + col0 + m * 4] = o4;
  }
}

extern "C" void kernel_launch(void* const* d_in, const int* in_sizes, int n_in,
                              void* d_out, int out_size, void* d_ws,
                              size_t ws_size, hipStream_t stream) {
  const float* patch = (const float*)d_in[0];
  const float* pixel = (const float*)d_in[1];
  const float* Wq = (const float*)d_in[2];
  const float* Wk = (const float*)d_in[3];
  const float* Wv = (const float*)d_in[4];
  const float* Wo = (const float*)d_in[5];
  const float* bo = (const float*)d_in[6];
  float* out = (float*)d_out;

  const size_t E = (size_t)2 * SEQ * DMODEL;  // 4,194,304
  const size_t W = (size_t)DMODEL * DMODEL;   // 1,048,576
  ushort* pb  = (ushort*)d_ws;      // patch bf16
  ushort* xb  = pb + E;             // pixel bf16
  ushort* wqt = xb + E;             // Wq^T * QSCALE bf16 [N][K]
  ushort* wkt = wqt + W;
  ushort* wvt = wkt + W;
  ushort* wot = wvt + W;            // live until mfma_gemm_out
  ushort* qws = wot + W;            // Q row-major [4096][1024] bf16
  ushort* kws = qws + E;            // K row-major [4096][1024] bf16
  ushort* vws = kws + E;            // V^T [bh][64][SEQ] bf16
  ushort* aws = vws + E;            // [4096][1024] row-major bf16

  prologue<<<dim3(32, 32, 6), dim3(32, 8), 0, stream>>>(
      patch, pixel, Wq, Wk, Wv, Wo, pb, xb, wqt, wkt, wvt, wot);
  mfma_gemm_qkv<<<dim3(8, 32, 3), 256, 0, stream>>>(pb, xb, wqt, wkt, wvt,
                                                    qws, kws, vws);
  flash_mfma<<<dim3(32, 16), 256, 0, stream>>>(qws, kws, vws, aws);
  mfma_gemm_out<<<dim3(8, 64), 256, 0, stream>>>(aws, wot, bo, out);
}

// Round 11
// 183.405 us; speedup vs baseline: 1.2026x; 1.1079x over previous
//
#include <hip/hip_runtime.h>

#define SEQ 2048
#define DMODEL 1024
#define HEADS 16
#define DH 64
// fold (1/sqrt(64)) * log2(e) into Wq so scores arrive in exp2 domain
#define QSCALE 0.180336880f

typedef __attribute__((ext_vector_type(8))) short short8;
typedef __attribute__((ext_vector_type(4))) float f32x4;
typedef __attribute__((ext_vector_type(16))) float f32x16;
typedef __attribute__((ext_vector_type(2))) unsigned int uint2v;
typedef __attribute__((ext_vector_type(4))) unsigned int uint4v;

__device__ __forceinline__ ushort f2bf(float x) {
  union { float f; unsigned u; } v; v.f = x;
  return (ushort)((v.u + 0x7fffu + ((v.u >> 16) & 1u)) >> 16);
}

// async global->LDS, 16B per lane. LDS dest = wave-uniform base + lane*16.
__device__ __forceinline__ void gld16(const ushort* g, ushort* l) {
  __builtin_amdgcn_global_load_lds(
      (const __attribute__((address_space(1))) unsigned int*)g,
      (__attribute__((address_space(3))) unsigned int*)l, 16, 0, 0);
}

// ---------------------------------------------------------------------------
// Fused prologue. z=0/1: fp32->bf16 cast of patch/pixel (4x float4/thread).
// z=2..5: transpose-cast Wq*QSCALE / Wk / Wv / Wo to [N][K] bf16.
// ---------------------------------------------------------------------------
__global__ __launch_bounds__(256) void prologue(
    const float* __restrict__ patch, const float* __restrict__ pixel,
    const float* __restrict__ W0, const float* __restrict__ W1,
    const float* __restrict__ W2, const float* __restrict__ W3,
    ushort* __restrict__ pb, ushort* __restrict__ xb,
    ushort* __restrict__ O0, ushort* __restrict__ O1,
    ushort* __restrict__ O2, ushort* __restrict__ O3) {
  const int z = blockIdx.z;
  const int tx = threadIdx.x, ty = threadIdx.y;
  if (z < 2) {
    const float4* in = (const float4*)(z ? pixel : patch);
    ushort4* out = (ushort4*)(z ? xb : pb);
    const int base = (blockIdx.y * 32 + blockIdx.x) * 256 + ty * 32 + tx;
#pragma unroll
    for (int rep = 0; rep < 4; ++rep) {
      const int i = base + rep * 262144;
      float4 f = in[i];
      out[i] = make_ushort4(f2bf(f.x), f2bf(f.y), f2bf(f.z), f2bf(f.w));
    }
    return;
  }
  __shared__ float tile[32][33];
  const int zz = z - 2;
  const float* in = zz == 0 ? W0 : zz == 1 ? W1 : zz == 2 ? W2 : W3;
  ushort* out = zz == 0 ? O0 : zz == 1 ? O1 : zz == 2 ? O2 : O3;
  const float scale = zz == 0 ? QSCALE : 1.0f;
  const int n0 = blockIdx.x * 32, k0 = blockIdx.y * 32;
#pragma unroll
  for (int i = 0; i < 4; ++i)
    tile[ty + i * 8][tx] = in[(size_t)(k0 + ty + i * 8) * DMODEL + n0 + tx];
  __syncthreads();
#pragma unroll
  for (int i = 0; i < 4; ++i)
    out[(size_t)(n0 + ty + i * 8) * DMODEL + k0 + tx] =
        f2bf(tile[tx][ty + i * 8] * scale);
}

// ---------------------------------------------------------------------------
// Fused Q/K/V projection GEMM, global_load_lds(16B) staging, XOR-swizzled on
// the GLOBAL side. 128x128 tile, BK=64, 4 waves. XCD-chunked block remap
// (T1): flat id%8 = XCD under round-robin dispatch; remap so each XCD owns
// row-panels 4k..4k+3 x all col-panels -> A-panels fetched into ONE L2
// instead of eight (r10 counters: FETCH 101 MB vs ~30 MB inputs; A-panel
// sharing blocks were spread across all 8 XCDs). Epilogues: r6 originals.
// ---------------------------------------------------------------------------
__global__ __launch_bounds__(256) void mfma_gemm_qkv(
    const ushort* __restrict__ pb, const ushort* __restrict__ xb,
    const ushort* __restrict__ wqt, const ushort* __restrict__ wkt,
    const ushort* __restrict__ wvt, ushort* __restrict__ qws,
    ushort* __restrict__ kws, ushort* __restrict__ vws) {
  __shared__ __align__(16) ushort As[128 * 64];
  __shared__ __align__(16) ushort Bs[128 * 64];
  const int z = blockIdx.z;
  const ushort* A = (z == 0) ? pb : xb;
  const ushort* Bt = (z == 0) ? wqt : (z == 1) ? wkt : wvt;

  const int t = threadIdx.x;
  const int w = t >> 6, lane = t & 63, ln = lane & 15, q = lane >> 4;
  const int wm = w & 1, wn = w >> 1;
  // XCD-chunked remap: 256 blocks/z = 32 row-panels x 8 col-panels.
  // xcd = flat%8; XCD k -> row-panels 4k..4k+3, col-panels 0..7 (bijective).
  const int flat = blockIdx.y * 8 + blockIdx.x;
  const int xcd = flat & 7, idx = flat >> 3;
  const int row0 = ((xcd << 2) | (idx & 3)) * 128;
  const int col0 = (idx >> 2) * 128;
  const int sw = ln & 7;

  f32x4 acc[4][4];
#pragma unroll
  for (int i = 0; i < 4; ++i)
#pragma unroll
    for (int j = 0; j < 4; ++j) acc[i][j] = (f32x4){0.f, 0.f, 0.f, 0.f};

  for (int k0 = 0; k0 < DMODEL; k0 += 64) {
    __syncthreads();  // prior frag reads done
#pragma unroll
    for (int rep = 0; rep < 4; ++rep) {
      const int u0 = rep * 256 + w * 64;
      const int u = u0 + lane;
      const int r = u >> 3, gl = (u & 7) ^ (r & 7);
      gld16(&A[(size_t)(row0 + r) * DMODEL + k0 + gl * 8], &As[u0 * 8]);
      gld16(&Bt[(size_t)(col0 + r) * DMODEL + k0 + gl * 8], &Bs[u0 * 8]);
    }
    __syncthreads();  // vmcnt drain
#pragma unroll
    for (int ks = 0; ks < 2; ++ks) {
      short8 af[4], bf[4];
#pragma unroll
      for (int rt = 0; rt < 4; ++rt)
        af[rt] = *(const short8*)&As[(wm * 64 + rt * 16 + ln) * 64 +
                                     (((ks * 4 + q) ^ sw) * 8)];
#pragma unroll
      for (int ct = 0; ct < 4; ++ct)
        bf[ct] = *(const short8*)&Bs[(wn * 64 + ct * 16 + ln) * 64 +
                                     (((ks * 4 + q) ^ sw) * 8)];
#pragma unroll
      for (int rt = 0; rt < 4; ++rt)
#pragma unroll
        for (int ct = 0; ct < 4; ++ct)
          acc[rt][ct] = __builtin_amdgcn_mfma_f32_16x16x32_bf16(af[rt], bf[ct],
                                                                acc[rt][ct], 0, 0, 0);
    }
  }

  if (z < 2) {
    ushort* dst = z == 0 ? qws : kws;  // row-major [4096][1024]
#pragma unroll
    for (int rt = 0; rt < 4; ++rt)
#pragma unroll
      for (int ct = 0; ct < 4; ++ct) {
        const int c = col0 + wn * 64 + ct * 16 + ln;
#pragma unroll
        for (int reg = 0; reg < 4; ++reg) {
          const int r = row0 + wm * 64 + rt * 16 + q * 4 + reg;
          dst[(size_t)r * DMODEL + c] = f2bf(acc[rt][ct][reg]);
        }
      }
  } else {
    // V^T: vws[bh][64][SEQ]
#pragma unroll
    for (int rt = 0; rt < 4; ++rt)
#pragma unroll
      for (int ct = 0; ct < 4; ++ct) {
        const int c = col0 + wn * 64 + ct * 16 + ln;
        const int hh = c >> 6, d = c & 63;
        const int r0 = row0 + wm * 64 + rt * 16 + q * 4;
        const int bb = r0 >> 11, s0 = r0 & (SEQ - 1);
        ushort4 u4 = make_ushort4(f2bf(acc[rt][ct][0]), f2bf(acc[rt][ct][1]),
                                  f2bf(acc[rt][ct][2]), f2bf(acc[rt][ct][3]));
        *(ushort4*)&vws[((size_t)(bb * HEADS + hh) * DH + d) * SEQ + s0] = u4;
      }
  }
}

// ---------------------------------------------------------------------------
// Flash attention v9 (round-6 EXACT, proven 45.9us): dual-stream dep-chain
// break -- each barrier region processes TWO K-tiles as independent register
// streams (A, B); scheduler fills A's softmax window with B's MFMA issue.
// 32x32x16, swapped QK^T, in-register softmax via cvt_pk+permlane32_swap,
// 2-buffer DMA, one __syncthreads per region. l_i as 4 partials.
// ---------------------------------------------------------------------------
__global__ __launch_bounds__(256, 2) void flash_mfma(
    const ushort* __restrict__ Qg, const ushort* __restrict__ Kg,
    const ushort* __restrict__ Vg, ushort* __restrict__ Og) {
  __shared__ __align__(16) ushort Kst[2][2][64 * 64];  // [buf][sub] 8 KB each
  __shared__ __align__(16) ushort Vst[2][2][64 * 64];

  const int t = threadIdx.x;
  const int w = t >> 6, lane = t & 63;
  const int l31 = lane & 31, hi = lane >> 5, l7 = lane & 7, l8 = lane >> 3;
  const int bh = blockIdx.x;  // 0..31 (XCD-pinning: id%8 = bh%8)
  const int qt = blockIdx.y;  // 0..15 (128-row Q tile)
  const int b = bh >> 4, h = bh & 15;

  const ushort* qrow = Qg + ((size_t)b * SEQ) * DMODEL + h * DH;  // [s][1024]
  const ushort* krow = Kg + ((size_t)b * SEQ) * DMODEL + h * DH;
  const ushort* vg = Vg + (size_t)bh * DH * SEQ;                  // [64][SEQ]

  // Q B-fragments: lane: qcol = l31, k = ks*16 + hi*8 + j  (row-major read)
  short8 qf[4];
#pragma unroll
  for (int ks = 0; ks < 4; ++ks)
    qf[ks] = *(const short8*)
        &qrow[(size_t)(qt * 128 + w * 32 + l31) * DMODEL + ks * 16 + hi * 8];

  f32x16 acc_o[2];
#pragma unroll
  for (int db = 0; db < 2; ++db)
#pragma unroll
    for (int e = 0; e < 16; ++e) acc_o[db][e] = 0.f;
  float l4[4] = {0.f, 0.f, 0.f, 0.f};

  // DMA assignment: w0: K f0-3, w1: K f4-7, w2: V f0-3, w3: V f4-7.
  // frag f covers 8 rows x 64 cols; lane: row f*8+l8, 16B chunk (l7^l8)
  // (global-side XOR swizzle; LDS dest is linear).
  const int fbase = (w & 1) * 4;
  const bool isV = (w >= 2);
  const int swz = (l7 ^ l8) * 8;

  auto stagePair = [&](int pt, int buf) {
#pragma unroll
    for (int st2 = 0; st2 < 2; ++st2) {
      const int tile = pt * 2 + st2;
#pragma unroll
      for (int i = 0; i < 4; ++i) {
        const int f = fbase + i;
        if (!isV)
          gld16(&krow[(size_t)(tile * 64 + f * 8 + l8) * DMODEL + swz],
                &Kst[buf][st2][f * 512]);
        else
          gld16(&vg[(size_t)(f * 8 + l8) * SEQ + tile * 64 + swz],
                &Vst[buf][st2][f * 512]);
      }
    }
  };

  stagePair(0, 0);
  __syncthreads();  // prologue DMA drained

  for (int pt = 0; pt < SEQ / 128; ++pt) {
    const int cur = pt & 1;
    // issue NEXT pair's DMA first (lands during this region's compute)
    if (pt + 1 < SEQ / 128) stagePair(pt + 1, cur ^ 1);

    const ushort* KcA = &Kst[cur][0][0];
    const ushort* KcB = &Kst[cur][1][0];
    const ushort* VcA = &Vst[cur][0][0];
    const ushort* VcB = &Vst[cur][1][0];

    // ---- QK^T for both streams (independent MFMA chains) ----
    f32x16 accsA[2], accsB[2];
#pragma unroll
    for (int kb = 0; kb < 2; ++kb)
#pragma unroll
      for (int e = 0; e < 16; ++e) {
        accsA[kb][e] = 0.f;
        accsB[kb][e] = 0.f;
      }
#pragma unroll
    for (int kb = 0; kb < 2; ++kb)
#pragma unroll
      for (int ks = 0; ks < 4; ++ks) {
        const int off = (kb * 32 + l31) * 64 + (((ks * 2 + hi) ^ l7) * 8);
        const short8 kfA = *(const short8*)&KcA[off];
        accsA[kb] = __builtin_amdgcn_mfma_f32_32x32x16_bf16(kfA, qf[ks],
                                                            accsA[kb], 0, 0, 0);
        const short8 kfB = *(const short8*)&KcB[off];
        accsB[kb] = __builtin_amdgcn_mfma_f32_32x32x16_bf16(kfB, qf[ks],
                                                            accsB[kb], 0, 0, 0);
      }

    // hoist stream A's V fragments
    short8 vfA[4][2];
#pragma unroll
    for (int sg = 0; sg < 4; ++sg)
#pragma unroll
      for (int db = 0; db < 2; ++db)
        vfA[sg][db] = *(const short8*)
            &VcA[(db * 32 + l31) * 64 + (((sg * 2 + hi) ^ l7) * 8)];

// softmax (exp2 in the pre-scaled domain) + in-register pack/permlane ->
// PV A-fragments. lane holds k = 8o + 4hi + 2u (+1) in word wq[o][u];
// slice sl needs k = 16sl + 8hi + j:
//   (word0,word2)=swap(wq[2sl][0], wq[2sl+1][0])
//   (word1,word3)=swap(wq[2sl][1], wq[2sl+1][1])
#define SOFTMAX_PACK(ACCS, PA)                                               \
  {                                                                          \
    _Pragma("unroll") for (int kb = 0; kb < 2; ++kb)                         \
        _Pragma("unroll") for (int e = 0; e < 16; ++e) {                     \
      const float p = __builtin_amdgcn_exp2f(ACCS[kb][e]);                   \
      ACCS[kb][e] = p;                                                       \
      l4[e & 3] += p;                                                        \
    }                                                                        \
    _Pragma("unroll") for (int kb = 0; kb < 2; ++kb) {                       \
      unsigned wq[4][2];                                                     \
      _Pragma("unroll") for (int o = 0; o < 4; ++o) {                        \
        asm("v_cvt_pk_bf16_f32 %0, %1, %2"                                   \
            : "=v"(wq[o][0])                                                 \
            : "v"(ACCS[kb][4 * o + 0]), "v"(ACCS[kb][4 * o + 1]));           \
        asm("v_cvt_pk_bf16_f32 %0, %1, %2"                                   \
            : "=v"(wq[o][1])                                                 \
            : "v"(ACCS[kb][4 * o + 2]), "v"(ACCS[kb][4 * o + 3]));           \
      }                                                                      \
      _Pragma("unroll") for (int sl = 0; sl < 2; ++sl) {                     \
        uint2v r02 = __builtin_amdgcn_permlane32_swap(                       \
            wq[2 * sl][0], wq[2 * sl + 1][0], false, false);                 \
        uint2v r13 = __builtin_amdgcn_permlane32_swap(                       \
            wq[2 * sl][1], wq[2 * sl + 1][1], false, false);                 \
        uint4v pk = {r02.x, r13.x, r02.y, r13.y};                            \
        PA[kb * 2 + sl] = __builtin_bit_cast(short8, pk);                    \
      }                                                                      \
    }                                                                        \
  }

    short8 paA[4];
    SOFTMAX_PACK(accsA, paA);

    // stream B's V fragments (after A's softmax to bound register pressure)
    short8 vfB[4][2];
#pragma unroll
    for (int sg = 0; sg < 4; ++sg)
#pragma unroll
      for (int db = 0; db < 2; ++db)
        vfB[sg][db] = *(const short8*)
            &VcB[(db * 32 + l31) * 64 + (((sg * 2 + hi) ^ l7) * 8)];

    // O += P_A @ V_A  (overlaps with B's softmax below per scheduler)
#pragma unroll
    for (int sg = 0; sg < 4; ++sg)
#pragma unroll
      for (int db = 0; db < 2; ++db)
        acc_o[db] = __builtin_amdgcn_mfma_f32_32x32x16_bf16(
            paA[sg], vfA[sg][db], acc_o[db], 0, 0, 0);

    short8 paB[4];
    SOFTMAX_PACK(accsB, paB);
#undef SOFTMAX_PACK

    // O += P_B @ V_B
#pragma unroll
    for (int sg = 0; sg < 4; ++sg)
#pragma unroll
      for (int db = 0; db < 2; ++db)
        acc_o[db] = __builtin_amdgcn_mfma_f32_32x32x16_bf16(
            paB[sg], vfB[sg][db], acc_o[db], 0, 0, 0);

    __syncthreads();  // reads of [cur] done + next pair's DMA drained
  }

  // epilogue: complete l over both lane halves, broadcast per output row,
  // normalize, write bf16 row-major [4096][1024]
  float l_i = (l4[0] + l4[1]) + (l4[2] + l4[3]);
  l_i += __shfl_xor(l_i, 32);
  const float inv = 1.0f / l_i;  // for q-column l31 (both halves hold it)
#pragma unroll
  for (int o = 0; o < 4; ++o)
#pragma unroll
    for (int r0 = 0; r0 < 4; ++r0) {
      const int row = o * 8 + r0 + 4 * hi;             // q-row of reg e=4o+r0
      const float invr = __shfl(inv, row, 64);         // lane 'row' holds it
      const int s = qt * 128 + w * 32 + row;
#pragma unroll
      for (int db = 0; db < 2; ++db)
        Og[(size_t)(b * SEQ + s) * DMODEL + h * DH + db * 32 + l31] =
            f2bf(acc_o[db][4 * o + r0] * invr);
    }
}

// ---------------------------------------------------------------------------
// Output projection: out = aws[4096,1024] @ WoT^T + bo (fp32). 64x128 tile,
// BK=64, global_load_lds staging, 512 blocks. XCD-chunked remap: XCD k owns
// row-panels 8k..8k+7 (A-panels fetched into one L2). r6 scalar epilogue.
// ---------------------------------------------------------------------------
__global__ __launch_bounds__(256) void mfma_gemm_out(const ushort* __restrict__ A,
                                                     const ushort* __restrict__ Bt,
                                                     const float* __restrict__ bias,
                                                     float* __restrict__ dst) {
  __shared__ __align__(16) ushort As[64 * 64];
  __shared__ __align__(16) ushort Bs[128 * 64];
  const int t = threadIdx.x;
  const int w = t >> 6, lane = t & 63, ln = lane & 15, q = lane >> 4;
  const int wm = w & 1, wn = w >> 1;
  // XCD-chunked remap: 512 blocks = 64 row-panels x 8 col-panels.
  const int flat = blockIdx.y * 8 + blockIdx.x;
  const int xcd = flat & 7, idx = flat >> 3;
  const int row0 = ((xcd << 3) | (idx & 7)) * 64;
  const int col0 = (idx >> 3) * 128;
  const int sw = ln & 7;

  f32x4 acc[2][4];
#pragma unroll
  for (int i = 0; i < 2; ++i)
#pragma unroll
    for (int j = 0; j < 4; ++j) acc[i][j] = (f32x4){0.f, 0.f, 0.f, 0.f};

  for (int k0 = 0; k0 < DMODEL; k0 += 64) {
    __syncthreads();
#pragma unroll
    for (int rep = 0; rep < 2; ++rep) {
      const int u0 = rep * 256 + w * 64;
      const int u = u0 + lane;
      const int r = u >> 3, gl = (u & 7) ^ (r & 7);
      gld16(&A[(size_t)(row0 + r) * DMODEL + k0 + gl * 8], &As[u0 * 8]);
    }
#pragma unroll
    for (int rep = 0; rep < 4; ++rep) {
      const int u0 = rep * 256 + w * 64;
      const int u = u0 + lane;
      const int r = u >> 3, gl = (u & 7) ^ (r & 7);
      gld16(&Bt[(size_t)(col0 + r) * DMODEL + k0 + gl * 8], &Bs[u0 * 8]);
    }
    __syncthreads();
#pragma unroll
    for (int ks = 0; ks < 2; ++ks) {
      short8 af[2], bf[4];
#pragma unroll
      for (int rt = 0; rt < 2; ++rt)
        af[rt] = *(const short8*)&As[(wm * 32 + rt * 16 + ln) * 64 +
                                     (((ks * 4 + q) ^ sw) * 8)];
#pragma unroll
      for (int ct = 0; ct < 4; ++ct)
        bf[ct] = *(const short8*)&Bs[(wn * 64 + ct * 16 + ln) * 64 +
                                     (((ks * 4 + q) ^ sw) * 8)];
#pragma unroll
      for (int rt = 0; rt < 2; ++rt)
#pragma unroll
        for (int ct = 0; ct < 4; ++ct)
          acc[rt][ct] = __builtin_amdgcn_mfma_f32_16x16x32_bf16(af[rt], bf[ct],
                                                                acc[rt][ct], 0, 0, 0);
    }
  }

#pragma unroll
  for (int rt = 0; rt < 2; ++rt)
#pragma unroll
    for (int ct = 0; ct < 4; ++ct) {
      const int c = col0 + wn * 64 + ct * 16 + ln;
      const float bi = bias[c];
#pragma unroll
      for (int reg = 0; reg < 4; ++reg) {
        const int r = row0 + wm * 32 + rt * 16 + q * 4 + reg;
        dst[(size_t)r * DMODEL + c] = acc[rt][ct][reg] + bi;
      }
    }
}

extern "C" void kernel_launch(void* const* d_in, const int* in_sizes, int n_in,
                              void* d_out, int out_size, void* d_ws,
                              size_t ws_size, hipStream_t stream) {
  const float* patch = (const float*)d_in[0];
  const float* pixel = (const float*)d_in[1];
  const float* Wq = (const float*)d_in[2];
  const float* Wk = (const float*)d_in[3];
  const float* Wv = (const float*)d_in[4];
  const float* Wo = (const float*)d_in[5];
  const float* bo = (const float*)d_in[6];
  float* out = (float*)d_out;

  const size_t E = (size_t)2 * SEQ * DMODEL;  // 4,194,304
  const size_t W = (size_t)DMODEL * DMODEL;   // 1,048,576
  ushort* pb  = (ushort*)d_ws;      // patch bf16
  ushort* xb  = pb + E;             // pixel bf16
  ushort* wqt = xb + E;             // Wq^T * QSCALE bf16 [N][K]
  ushort* wkt = wqt + W;
  ushort* wvt = wkt + W;
  ushort* wot = wvt + W;            // live until mfma_gemm_out
  ushort* qws = wot + W;            // Q row-major [4096][1024] bf16
  ushort* kws = qws + E;            // K row-major [4096][1024] bf16
  ushort* vws = kws + E;            // V^T [bh][64][SEQ] bf16
  ushort* aws = vws + E;            // [4096][1024] row-major bf16

  prologue<<<dim3(32, 32, 6), dim3(32, 8), 0, stream>>>(
      patch, pixel, Wq, Wk, Wv, Wo, pb, xb, wqt, wkt, wvt, wot);
  mfma_gemm_qkv<<<dim3(8, 32, 3), 256, 0, stream>>>(pb, xb, wqt, wkt, wvt,
                                                    qws, kws, vws);
  flash_mfma<<<dim3(32, 16), 256, 0, stream>>>(qws, kws, vws, aws);
  mfma_gemm_out<<<dim3(8, 64), 256, 0, stream>>>(aws, wot, bo, out);
}